// Round 13
// baseline (84.127 us; speedup 1.0000x reference)
//
#include <hip/hip_runtime.h>

// phi (B,2,H,W) f32 -> out (B,1,H,W) f32 ; splat ones with bilinear weights, wrap BC.
// Gather formulation, scalar tent weights, RB=8 multi-row amortization, store-only
// commit (exclusive ownership -> no commit atomics, no output memset), compile-time-
// pruned (t,m) pairs.
// R13: sched_barrier(0) at the END of each t-iteration forces t-major association.
// (R12's VGPR=44 proved the compiler went m-major, recomputing the 14-op col-tent
// vector per (t,m) pair -- 42 redundant evaluations/wave == the 2x op-count gap.)
// Wide-displacement sources (|dx|>=3 or |dy|>=3, P~0.5%) -> per-(srow,chunk) byte
// flags (plain stores; R7/R8: contended counter == 900us wall), flushed by a second
// kernel with scattered uncontended atomics.
constexpr int H = 2048, W = 2048;
constexpr int HW = H * W;
constexpr int OUTW = 56;                    // output cols per wave (64 lanes - 8 halo)
constexpr int NCH = (W + OUTW - 1) / OUTW;  // 37 col-chunks (last ragged)
constexpr int RB  = 8;                      // owned rows per wave
constexpr int WPB = 4;                      // waves per block
constexpr int ROWSPB = RB * WPB;            // 32 rows per block
constexpr int NSRC = RB + 6;                // 14 scanned source rows per wave

__global__ __launch_bounds__(256, 3)        // 3 waves/EU: ~170-VGPR budget
void splat_gather8t(const float* __restrict__ phi, float* __restrict__ out,
                    unsigned char* __restrict__ flags) {
    int wid  = threadIdx.x >> 6;
    int lane = threadIdx.x & 63;

    const int rgPerImg = H / ROWSPB;        // 64
    int bid = blockIdx.x;
    int b   = bid / (NCH * rgPerImg);
    int rem = bid - b * (NCH * rgPerImg);
    int c0i = rem / rgPerImg;
    int rg  = rem - c0i * rgPerImg;
    int r0  = rg * ROWSPB + wid * RB;       // first owned row of this wave
    int c0  = c0i * OUTW;

    const float* phiB = phi + (size_t)b * 2 * HW;
    float* outb = out + (size_t)b * HW;

    int scu = c0 - 4 + lane;                // unwrapped source col of this lane
    int scw = scu & (W - 1);                // wrapped col for loads
    bool ownedCol = (lane >= 4) && (lane < 4 + OUTW) && (scu < W);

    // prefetch all candidate source rows up front
    float dxv[NSRC], dyv[NSRC];
    #pragma unroll
    for (int t = 0; t < NSRC; ++t) {
        int srow = (r0 + t - 3) & (H - 1);
        dxv[t] = phiB[(size_t)srow * W + scw];
        dyv[t] = phiB[(size_t)HW + (size_t)srow * W + scw];
    }

    float slot[RB][7];
    #pragma unroll
    for (int m = 0; m < RB; ++m)
        #pragma unroll
        for (int k = 0; k < 7; ++k) slot[m][k] = 0.0f;

    #pragma unroll
    for (int t = 0; t < NSRC; ++t) {
        float dx = dxv[t], dy = dyv[t];
        bool valid = (__builtin_fabsf(dx) < 3.0f) && (__builtin_fabsf(dy) < 3.0f);
        float dyM = valid ? dy : 16384.0f;   // invalid -> all col tents 0 -> flush only

        // scalar col tent weights toward offsets ko = k-3 (computed ONCE per t)
        float ct[7];
        #pragma unroll
        for (int k = 0; k < 7; ++k) {
            float d = dyM - (float)(k - 3);
            ct[k] = __builtin_fmaxf(1.0f - __builtin_fabsf(d), 0.0f);
        }

        // row tents toward owned rows + rank-1 accumulate (pruned: rw==0 if t-m not in [0,6])
        #pragma unroll
        for (int m = 0; m < RB; ++m) {
            if (t - m < 0 || t - m > 6) continue;   // compile-time DCE under unroll
            float dist = dx + (float)(t - 3 - m);   // x - (r0+m), unwrapped
            float rw = __builtin_fmaxf(1.0f - __builtin_fabsf(dist), 0.0f);
            #pragma unroll
            for (int k = 0; k < 7; ++k)
                slot[m][k] = __builtin_fmaf(rw, ct[k], slot[m][k]);
        }

        // flag this wave's owned source rows (t in [3,3+RB)): plain byte store, no atomics
        if (t >= 3 && t < 3 + RB) {
            bool need = (!valid) && ownedCol;
            unsigned long long mask = __ballot(need);
            if (lane == 0) {
                int srow = (r0 + t - 3) & (H - 1);
                flags[(size_t)(b * H + srow) * NCH + c0i] = (mask != 0ull) ? 1 : 0;
            }
        }

        // pin this t-iteration as one scheduling region: ct is computed once and
        // shared by all m-updates above; forbids m-major reassociation/remat.
        __builtin_amdgcn_sched_barrier(0);
    }

    // route column slots and commit with plain stores (exclusive ownership)
    #pragma unroll
    for (int m = 0; m < RB; ++m) {
        float v = 0.0f;
        #pragma unroll
        for (int k = 0; k < 7; ++k)
            v += __shfl(slot[m][k], lane - (k - 3));
        if (ownedCol)
            outb[(size_t)(r0 + m) * W + scu] = v;
    }
}

// Wave-batched flush: each wave reads 16 flags, processes flagged chunks (full wave each).
__global__ __launch_bounds__(256)
void flush_flagged(const float* __restrict__ phi, const unsigned char* __restrict__ flags,
                   float* __restrict__ out) {
    int wid  = threadIdx.x >> 6;
    int lane = threadIdx.x & 63;
    unsigned base = ((unsigned)blockIdx.x * WPB + (unsigned)wid) * 16u;  // 16 chunks/wave

    unsigned char f = (lane < 16) ? flags[base + (unsigned)lane] : (unsigned char)0;
    unsigned long long mask = __ballot(f != 0);

    while (mask) {
        int bit = (int)(__ffsll((long long)mask) - 1);
        mask &= mask - 1ull;
        unsigned chunk = base + (unsigned)bit;

        int c0i  = (int)(chunk % (unsigned)NCH);
        unsigned bs = chunk / (unsigned)NCH;
        int srow = (int)(bs & (H - 1));
        int b    = (int)(bs >> 11);            // H = 2048

        int col = c0i * OUTW + lane;           // lanes [0,56) own cols of this chunk
        if (lane < OUTW && col < W) {
            const float* phiB = phi + (size_t)b * 2 * HW;
            float dx = phiB[(size_t)srow * W + col];
            float dy = phiB[(size_t)HW + (size_t)srow * W + col];
            if (!((__builtin_fabsf(dx) < 3.0f) && (__builtin_fabsf(dy) < 3.0f))) {
                float* outb = out + (size_t)b * HW;
                float x = (float)srow + dx;
                float y = (float)col + dy;
                float x0 = floorf(x), y0 = floorf(y);
                float wx1 = x - x0, wx0 = 1.0f - wx1;
                float wy1 = y - y0, wy0 = 1.0f - wy1;
                int gx0 = ((int)x0) & (H - 1);
                int gx1 = (gx0 + 1) & (H - 1);
                int gy0 = ((int)y0) & (W - 1);
                int gy1 = (gy0 + 1) & (W - 1);
                atomicAdd(outb + (size_t)gx0 * W + gy0, wx0 * wy0);
                atomicAdd(outb + (size_t)gx0 * W + gy1, wx0 * wy1);
                atomicAdd(outb + (size_t)gx1 * W + gy0, wx1 * wy0);
                atomicAdd(outb + (size_t)gx1 * W + gy1, wx1 * wy1);
            }
        }
    }
}

extern "C" void kernel_launch(void* const* d_in, const int* in_sizes, int n_in,
                              void* d_out, int out_size, void* d_ws, size_t ws_size,
                              hipStream_t stream) {
    const float* phi = (const float*)d_in[0];
    float* out = (float*)d_out;
    unsigned char* flags = (unsigned char*)d_ws;   // B*H*NCH bytes, fully rewritten per call

    int B = out_size / HW;
    int grid = B * NCH * (H / ROWSPB);             // 4 * 37 * 64 = 9472 blocks
    splat_gather8t<<<grid, 256, 0, stream>>>(phi, out, flags);

    long long nChunks = (long long)B * H * NCH;    // 303,104 = 4736 * 64
    int grid2 = (int)(nChunks / (WPB * 16));       // 4736 blocks (16 chunks per wave)
    flush_flagged<<<grid2, 256, 0, stream>>>(phi, flags, out);
}

// Round 14
// 83.163 us; speedup vs baseline: 1.0116x; 1.0116x over previous
//
#include <hip/hip_runtime.h>

// phi (B,2,H,W) f32 -> out (B,1,H,W) f32 ; splat ones with bilinear weights, wrap BC.
// Gather formulation, scalar tent weights, RB=8 multi-row amortization, store-only
// commit (exclusive ownership -> no commit atomics, no output memset), compile-time-
// pruned (t,m) pairs.
// R14: empty inline-asm "+v" pins on the prefetched dx/dy AND the per-t col-tent
// vector ct[] make those values opaque defs -- the compiler can no longer go m-major
// and rematerialize ct per (t,m) (R12/R13: VGPR stuck at 44 == m-major remat, ~880
// redundant wave-ops). Forces the intended t-major schedule: ct computed once per t.
// Wide-displacement sources (|dx|>=3 or |dy|>=3, P~0.5%) -> per-(srow,chunk) byte
// flags (plain stores; R7/R8: contended counter == 900us wall), flushed by a second
// kernel with scattered uncontended atomics.
constexpr int H = 2048, W = 2048;
constexpr int HW = H * W;
constexpr int OUTW = 56;                    // output cols per wave (64 lanes - 8 halo)
constexpr int NCH = (W + OUTW - 1) / OUTW;  // 37 col-chunks (last ragged)
constexpr int RB  = 8;                      // owned rows per wave
constexpr int WPB = 4;                      // waves per block
constexpr int ROWSPB = RB * WPB;            // 32 rows per block
constexpr int NSRC = RB + 6;                // 14 scanned source rows per wave

__global__ __launch_bounds__(256, 3)        // 3 waves/EU: ~170-VGPR budget, ~110 live
void splat_gather8o(const float* __restrict__ phi, float* __restrict__ out,
                    unsigned char* __restrict__ flags) {
    int wid  = threadIdx.x >> 6;
    int lane = threadIdx.x & 63;

    const int rgPerImg = H / ROWSPB;        // 64
    int bid = blockIdx.x;
    int b   = bid / (NCH * rgPerImg);
    int rem = bid - b * (NCH * rgPerImg);
    int c0i = rem / rgPerImg;
    int rg  = rem - c0i * rgPerImg;
    int r0  = rg * ROWSPB + wid * RB;       // first owned row of this wave
    int c0  = c0i * OUTW;

    const float* phiB = phi + (size_t)b * 2 * HW;
    float* outb = out + (size_t)b * HW;

    int scu = c0 - 4 + lane;                // unwrapped source col of this lane
    int scw = scu & (W - 1);                // wrapped col for loads
    bool ownedCol = (lane >= 4) && (lane < 4 + OUTW) && (scu < W);

    // prefetch all candidate source rows; opaque pins force completion here and
    // keep all 28 values live in VGPRs (no per-m reload, single vmcnt exposure)
    float dxv[NSRC], dyv[NSRC];
    #pragma unroll
    for (int t = 0; t < NSRC; ++t) {
        int srow = (r0 + t - 3) & (H - 1);
        dxv[t] = phiB[(size_t)srow * W + scw];
        dyv[t] = phiB[(size_t)HW + (size_t)srow * W + scw];
    }
    #pragma unroll
    for (int t = 0; t < NSRC; ++t)
        asm volatile("" : "+v"(dxv[t]), "+v"(dyv[t]));

    float slot[RB][7];
    #pragma unroll
    for (int m = 0; m < RB; ++m)
        #pragma unroll
        for (int k = 0; k < 7; ++k) slot[m][k] = 0.0f;

    #pragma unroll
    for (int t = 0; t < NSRC; ++t) {
        float dx = dxv[t], dy = dyv[t];
        bool valid = (__builtin_fabsf(dx) < 3.0f) && (__builtin_fabsf(dy) < 3.0f);
        float dyM = valid ? dy : 16384.0f;   // invalid -> all col tents 0 -> flush only

        // scalar col tent weights toward offsets ko = k-3, computed ONCE per t;
        // the opaque pin forbids rematerialization inside the m-loop
        float ct[7];
        #pragma unroll
        for (int k = 0; k < 7; ++k) {
            float d = dyM - (float)(k - 3);
            ct[k] = __builtin_fmaxf(1.0f - __builtin_fabsf(d), 0.0f);
        }
        #pragma unroll
        for (int k = 0; k < 7; ++k)
            asm volatile("" : "+v"(ct[k]));

        // row tents toward owned rows + rank-1 accumulate (pruned: rw==0 if t-m not in [0,6])
        #pragma unroll
        for (int m = 0; m < RB; ++m) {
            if (t - m < 0 || t - m > 6) continue;   // compile-time DCE under unroll
            float dist = dx + (float)(t - 3 - m);   // x - (r0+m), unwrapped
            float rw = __builtin_fmaxf(1.0f - __builtin_fabsf(dist), 0.0f);
            #pragma unroll
            for (int k = 0; k < 7; ++k)
                slot[m][k] = __builtin_fmaf(rw, ct[k], slot[m][k]);
        }

        // flag this wave's owned source rows (t in [3,3+RB)): plain byte store, no atomics
        if (t >= 3 && t < 3 + RB) {
            bool need = (!valid) && ownedCol;
            unsigned long long mask = __ballot(need);
            if (lane == 0) {
                int srow = (r0 + t - 3) & (H - 1);
                flags[(size_t)(b * H + srow) * NCH + c0i] = (mask != 0ull) ? 1 : 0;
            }
        }
    }

    // route column slots and commit with plain stores (exclusive ownership)
    #pragma unroll
    for (int m = 0; m < RB; ++m) {
        float v = 0.0f;
        #pragma unroll
        for (int k = 0; k < 7; ++k)
            v += __shfl(slot[m][k], lane - (k - 3));
        if (ownedCol)
            outb[(size_t)(r0 + m) * W + scu] = v;
    }
}

// Wave-batched flush: each wave reads 16 flags, processes flagged chunks (full wave each).
__global__ __launch_bounds__(256)
void flush_flagged(const float* __restrict__ phi, const unsigned char* __restrict__ flags,
                   float* __restrict__ out) {
    int wid  = threadIdx.x >> 6;
    int lane = threadIdx.x & 63;
    unsigned base = ((unsigned)blockIdx.x * WPB + (unsigned)wid) * 16u;  // 16 chunks/wave

    unsigned char f = (lane < 16) ? flags[base + (unsigned)lane] : (unsigned char)0;
    unsigned long long mask = __ballot(f != 0);

    while (mask) {
        int bit = (int)(__ffsll((long long)mask) - 1);
        mask &= mask - 1ull;
        unsigned chunk = base + (unsigned)bit;

        int c0i  = (int)(chunk % (unsigned)NCH);
        unsigned bs = chunk / (unsigned)NCH;
        int srow = (int)(bs & (H - 1));
        int b    = (int)(bs >> 11);            // H = 2048

        int col = c0i * OUTW + lane;           // lanes [0,56) own cols of this chunk
        if (lane < OUTW && col < W) {
            const float* phiB = phi + (size_t)b * 2 * HW;
            float dx = phiB[(size_t)srow * W + col];
            float dy = phiB[(size_t)HW + (size_t)srow * W + col];
            if (!((__builtin_fabsf(dx) < 3.0f) && (__builtin_fabsf(dy) < 3.0f))) {
                float* outb = out + (size_t)b * HW;
                float x = (float)srow + dx;
                float y = (float)col + dy;
                float x0 = floorf(x), y0 = floorf(y);
                float wx1 = x - x0, wx0 = 1.0f - wx1;
                float wy1 = y - y0, wy0 = 1.0f - wy1;
                int gx0 = ((int)x0) & (H - 1);
                int gx1 = (gx0 + 1) & (H - 1);
                int gy0 = ((int)y0) & (W - 1);
                int gy1 = (gy0 + 1) & (W - 1);
                atomicAdd(outb + (size_t)gx0 * W + gy0, wx0 * wy0);
                atomicAdd(outb + (size_t)gx0 * W + gy1, wx0 * wy1);
                atomicAdd(outb + (size_t)gx1 * W + gy0, wx1 * wy0);
                atomicAdd(outb + (size_t)gx1 * W + gy1, wx1 * wy1);
            }
        }
    }
}

extern "C" void kernel_launch(void* const* d_in, const int* in_sizes, int n_in,
                              void* d_out, int out_size, void* d_ws, size_t ws_size,
                              hipStream_t stream) {
    const float* phi = (const float*)d_in[0];
    float* out = (float*)d_out;
    unsigned char* flags = (unsigned char*)d_ws;   // B*H*NCH bytes, fully rewritten per call

    int B = out_size / HW;
    int grid = B * NCH * (H / ROWSPB);             // 4 * 37 * 64 = 9472 blocks
    splat_gather8o<<<grid, 256, 0, stream>>>(phi, out, flags);

    long long nChunks = (long long)B * H * NCH;    // 303,104 = 4736 * 64
    int grid2 = (int)(nChunks / (WPB * 16));       // 4736 blocks (16 chunks per wave)
    flush_flagged<<<grid2, 256, 0, stream>>>(phi, flags, out);
}